// Round 1
// baseline (2616.968 us; speedup 1.0000x reference)
//
#include <hip/hip_runtime.h>
#include <math.h>

#define BATCH 16
#define SEQ   1024
#define DIM   2048
#define EPS_F 0.1f
#define INV_EPS 10.0f
#define N_ITER 100

typedef short bf16x8 __attribute__((ext_vector_type(8)));
typedef float f32x4  __attribute__((ext_vector_type(4)));

__device__ inline float bf16_to_f(unsigned short u) {
    unsigned int x = ((unsigned int)u) << 16;
    return __uint_as_float(x);
}
__device__ inline unsigned short f_to_bf16(float f) {
    unsigned int x = __float_as_uint(f);
    unsigned int lsb = (x >> 16) & 1u;
    x += 0x7fffu + lsb;               // round-to-nearest-even
    return (unsigned short)(x >> 16);
}

// ---------------- v = 1 init ----------------
__global__ void init_v(float* __restrict__ v) {
    v[blockIdx.x * 256 + threadIdx.x] = 1.0f;
}

// ---------------- normalize + cast to bf16 ----------------
// one block per row (2048 floats); grid = 2 * 16 * 1024
__global__ __launch_bounds__(256) void normalize_kernel(
    const float* __restrict__ student, const float* __restrict__ teacher,
    unsigned short* __restrict__ Sn, unsigned short* __restrict__ Tn)
{
    int rowid  = blockIdx.x;
    int tensor = rowid >> 14;         // 0: student, 1: teacher
    int row    = rowid & 16383;
    const float* src = tensor ? teacher : student;
    unsigned short* dst = tensor ? Tn : Sn;
    const float4* p4 = (const float4*)(src + (size_t)row * DIM);
    int t = threadIdx.x;

    float4 a = p4[t];          // cols 4t .. 4t+3
    float4 b = p4[t + 256];    // cols 1024+4t ..
    float ss = a.x*a.x + a.y*a.y + a.z*a.z + a.w*a.w
             + b.x*b.x + b.y*b.y + b.z*b.z + b.w*b.w;
    #pragma unroll
    for (int m = 32; m; m >>= 1) ss += __shfl_xor(ss, m, 64);
    __shared__ float wss[4];
    if ((t & 63) == 0) wss[t >> 6] = ss;
    __syncthreads();
    float rn = 1.0f / fmaxf(sqrtf(wss[0] + wss[1] + wss[2] + wss[3]), 1e-12f);

    unsigned short o1[4], o2[4];
    o1[0] = f_to_bf16(a.x * rn); o1[1] = f_to_bf16(a.y * rn);
    o1[2] = f_to_bf16(a.z * rn); o1[3] = f_to_bf16(a.w * rn);
    o2[0] = f_to_bf16(b.x * rn); o2[1] = f_to_bf16(b.y * rn);
    o2[2] = f_to_bf16(b.z * rn); o2[3] = f_to_bf16(b.w * rn);
    unsigned short* d = dst + (size_t)row * DIM;
    *(uint2*)(d + 4*t)        = *(uint2*)o1;
    *(uint2*)(d + 1024 + 4*t) = *(uint2*)o2;
}

// ---------------- batched GEMM -> K = exp(-C/eps), bf16 ----------------
// C[b][i][j] = 0.5 - 0.5 * (Tn_i . Sn_j).  128x128 tiles, BK=32, 4 waves.
#define TM  128
#define BK  32
#define LDK 40   // padded bf16 row stride (2-way-max bank aliasing on b128 reads)

__global__ __launch_bounds__(256) void gemm_cost_kernel(
    const unsigned short* __restrict__ Tn, const unsigned short* __restrict__ Sn,
    unsigned short* __restrict__ Kmat)
{
    __shared__ unsigned short As[TM * LDK];
    __shared__ unsigned short Bs[TM * LDK];

    int bid  = blockIdx.x;          // 16 batches * 64 tiles
    int b    = bid >> 6;
    int tile = bid & 63;
    int tm0  = (tile >> 3) * TM;
    int tn0  = (tile & 7)  * TM;

    const unsigned short* Ab = Tn + (size_t)b * SEQ * DIM;
    const unsigned short* Bb = Sn + (size_t)b * SEQ * DIM;

    int t    = threadIdx.x;
    int w    = t >> 6;
    int l    = t & 63;
    int mq   = (w >> 1) * 64;
    int nq   = (w & 1)  * 64;
    int lrow = l & 15;
    int kg   = l >> 4;              // 0..3

    int srow = t >> 2;              // staging row 0..63 (and +64)
    int sseg = t & 3;               // 16B segment within 64B row chunk

    f32x4 acc[4][4];
    #pragma unroll
    for (int i = 0; i < 4; i++)
        #pragma unroll
        for (int j = 0; j < 4; j++)
            acc[i][j] = (f32x4){0.f, 0.f, 0.f, 0.f};

    for (int k0 = 0; k0 < DIM; k0 += BK) {
        const int4 va0 = *(const int4*)(Ab + (size_t)(tm0 + srow)      * DIM + k0 + sseg * 8);
        const int4 va1 = *(const int4*)(Ab + (size_t)(tm0 + srow + 64) * DIM + k0 + sseg * 8);
        const int4 vb0 = *(const int4*)(Bb + (size_t)(tn0 + srow)      * DIM + k0 + sseg * 8);
        const int4 vb1 = *(const int4*)(Bb + (size_t)(tn0 + srow + 64) * DIM + k0 + sseg * 8);
        __syncthreads();  // previous iteration's reads done
        *(int4*)&As[(srow)      * LDK + sseg * 8] = va0;
        *(int4*)&As[(srow + 64) * LDK + sseg * 8] = va1;
        *(int4*)&Bs[(srow)      * LDK + sseg * 8] = vb0;
        *(int4*)&Bs[(srow + 64) * LDK + sseg * 8] = vb1;
        __syncthreads();

        bf16x8 af[4], bfr[4];
        #pragma unroll
        for (int i = 0; i < 4; i++)
            af[i] = *(const bf16x8*)&As[(mq + i * 16 + lrow) * LDK + kg * 8];
        #pragma unroll
        for (int j = 0; j < 4; j++)
            bfr[j] = *(const bf16x8*)&Bs[(nq + j * 16 + lrow) * LDK + kg * 8];
        #pragma unroll
        for (int i = 0; i < 4; i++)
            #pragma unroll
            for (int j = 0; j < 4; j++)
                acc[i][j] = __builtin_amdgcn_mfma_f32_16x16x32_bf16(af[i], bfr[j], acc[i][j], 0, 0, 0);
    }

    // epilogue: C/D layout col = lane&15, row = (lane>>4)*4 + reg
    unsigned short* Kb = Kmat + ((size_t)b << 20);
    #pragma unroll
    for (int i = 0; i < 4; i++) {
        #pragma unroll
        for (int j = 0; j < 4; j++) {
            int gcol = tn0 + nq + j * 16 + lrow;
            #pragma unroll
            for (int r = 0; r < 4; r++) {
                int grow = tm0 + mq + i * 16 + kg * 4 + r;
                float cosv = acc[i][j][r];
                float cost = 0.5f - 0.5f * cosv;
                Kb[((size_t)grow << 10) + gcol] = f_to_bf16(__expf(-cost * INV_EPS));
            }
        }
    }
}

// ---------------- Sinkhorn row pass: u_i = a / sum_j K_ij v_j ----------------
// one wave per row; 4 rows per block; grid = 16 * 256
__global__ __launch_bounds__(256) void sinkhorn_row(
    const unsigned short* __restrict__ Kmat, const float* __restrict__ v,
    float* __restrict__ u)
{
    int bid = blockIdx.x;
    int b   = bid >> 8;
    int row = ((bid & 255) << 2) + (threadIdx.x >> 6);
    int l   = threadIdx.x & 63;
    const unsigned short* kr = Kmat + ((size_t)b << 20) + ((size_t)row << 10);
    const float* vb = v + (b << 10);

    int4 k1 = *(const int4*)(kr + l * 8);
    int4 k2 = *(const int4*)(kr + 512 + l * 8);
    float4 v1a = *(const float4*)(vb + l * 8);
    float4 v1b = *(const float4*)(vb + l * 8 + 4);
    float4 v2a = *(const float4*)(vb + 512 + l * 8);
    float4 v2b = *(const float4*)(vb + 512 + l * 8 + 4);

    const unsigned short* k1s = (const unsigned short*)&k1;
    const unsigned short* k2s = (const unsigned short*)&k2;
    float s = 0.f;
    s += bf16_to_f(k1s[0]) * v1a.x; s += bf16_to_f(k1s[1]) * v1a.y;
    s += bf16_to_f(k1s[2]) * v1a.z; s += bf16_to_f(k1s[3]) * v1a.w;
    s += bf16_to_f(k1s[4]) * v1b.x; s += bf16_to_f(k1s[5]) * v1b.y;
    s += bf16_to_f(k1s[6]) * v1b.z; s += bf16_to_f(k1s[7]) * v1b.w;
    s += bf16_to_f(k2s[0]) * v2a.x; s += bf16_to_f(k2s[1]) * v2a.y;
    s += bf16_to_f(k2s[2]) * v2a.z; s += bf16_to_f(k2s[3]) * v2a.w;
    s += bf16_to_f(k2s[4]) * v2b.x; s += bf16_to_f(k2s[5]) * v2b.y;
    s += bf16_to_f(k2s[6]) * v2b.z; s += bf16_to_f(k2s[7]) * v2b.w;

    #pragma unroll
    for (int m = 32; m; m >>= 1) s += __shfl_xor(s, m, 64);
    if (l == 0) u[(b << 10) + row] = (1.0f / 1024.0f) / s;
}

// ---------------- Sinkhorn col pass: v_j = b / sum_i K_ij u_i ----------------
// block: 64 cols x 4 row-groups of 256 rows; grid = 16 batches * 16 col-chunks
__global__ __launch_bounds__(256) void sinkhorn_col(
    const unsigned short* __restrict__ Kmat, const float* __restrict__ u,
    float* __restrict__ v)
{
    int bid = blockIdx.x;
    int b   = bid >> 4;
    int c0  = (bid & 15) << 6;
    int t   = threadIdx.x;
    int col = c0 + (t & 63);
    int rg  = t >> 6;
    const unsigned short* kc = Kmat + ((size_t)b << 20) + col;
    const float* ub = u + (b << 10);

    float s = 0.f;
    int i0 = rg << 8;
    #pragma unroll 8
    for (int i = i0; i < i0 + 256; i++)
        s += bf16_to_f(kc[(size_t)i << 10]) * ub[i];

    __shared__ float part[4][64];
    part[rg][t & 63] = s;
    __syncthreads();
    if (t < 64) {
        float tot = part[0][t] + part[1][t] + part[2][t] + part[3][t];
        v[(b << 10) + c0 + t] = (1.0f / 1024.0f) / tot;
    }
}

// ---------------- loss = mean_b sum_ij u_i K_ij v_j * (-eps ln K_ij) ----------------
__global__ __launch_bounds__(256) void loss_partial(
    const unsigned short* __restrict__ Kmat, const float* __restrict__ u,
    const float* __restrict__ v, float* __restrict__ partials)
{
    int tid = blockIdx.x * 256 + threadIdx.x;   // 0..262143
    float acc = 0.f;
    #pragma unroll
    for (int it = 0; it < 8; it++) {
        size_t e0 = ((size_t)(it * 262144 + tid)) * 8;
        int b  = (int)(e0 >> 20);
        int i  = (int)((e0 >> 10) & 1023);
        int j0 = (int)(e0 & 1023);
        int4 kv = *(const int4*)(Kmat + e0);
        float ui = u[(b << 10) + i];
        const float* vb = v + (b << 10) + j0;
        float4 va  = *(const float4*)vb;
        float4 vb4 = *(const float4*)(vb + 4);
        float vj[8] = {va.x, va.y, va.z, va.w, vb4.x, vb4.y, vb4.z, vb4.w};
        const unsigned short* ks = (const unsigned short*)&kv;
        #pragma unroll
        for (int q = 0; q < 8; q++) {
            float kf = bf16_to_f(ks[q]);
            float C  = -EPS_F * __logf(kf);
            acc += ui * vj[q] * kf * C;
        }
    }
    #pragma unroll
    for (int m = 32; m; m >>= 1) acc += __shfl_xor(acc, m, 64);
    __shared__ float wp[4];
    if ((threadIdx.x & 63) == 0) wp[threadIdx.x >> 6] = acc;
    __syncthreads();
    if (threadIdx.x == 0) partials[blockIdx.x] = wp[0] + wp[1] + wp[2] + wp[3];
}

__global__ __launch_bounds__(256) void loss_final(
    const float* __restrict__ partials, float* __restrict__ out)
{
    float s = 0.f;
    for (int i = threadIdx.x; i < 1024; i += 256) s += partials[i];
    #pragma unroll
    for (int m = 32; m; m >>= 1) s += __shfl_xor(s, m, 64);
    __shared__ float wp[4];
    if ((threadIdx.x & 63) == 0) wp[threadIdx.x >> 6] = s;
    __syncthreads();
    if (threadIdx.x == 0) out[0] = (wp[0] + wp[1] + wp[2] + wp[3]) * (1.0f / 16.0f);
}

extern "C" void kernel_launch(void* const* d_in, const int* in_sizes, int n_in,
                              void* d_out, int out_size, void* d_ws, size_t ws_size,
                              hipStream_t stream) {
    const float* student = (const float*)d_in[0];
    const float* teacher = (const float*)d_in[1];
    float* out = (float*)d_out;
    char* ws = (char*)d_ws;

    // ws layout (bytes)
    unsigned short* Tn   = (unsigned short*)(ws);                     // 64 MB
    unsigned short* Sn   = (unsigned short*)(ws + 67108864);          // 64 MB
    unsigned short* Kmat = (unsigned short*)(ws + 134217728);         // 32 MB
    float* u        = (float*)(ws + 167772160);                       // 64 KB
    float* v        = (float*)(ws + 167772160 + 65536);               // 64 KB
    float* partials = (float*)(ws + 167772160 + 131072);              // 4 KB

    hipLaunchKernelGGL(init_v, dim3(64), dim3(256), 0, stream, v);
    hipLaunchKernelGGL(normalize_kernel, dim3(32768), dim3(256), 0, stream,
                       student, teacher, Sn, Tn);
    hipLaunchKernelGGL(gemm_cost_kernel, dim3(1024), dim3(256), 0, stream, Tn, Sn, Kmat);
    for (int it = 0; it < N_ITER; it++) {
        hipLaunchKernelGGL(sinkhorn_row, dim3(4096), dim3(256), 0, stream, Kmat, v, u);
        hipLaunchKernelGGL(sinkhorn_col, dim3(256), dim3(256), 0, stream, Kmat, u, v);
    }
    hipLaunchKernelGGL(loss_partial, dim3(1024), dim3(256), 0, stream, Kmat, u, v, partials);
    hipLaunchKernelGGL(loss_final, dim3(1), dim3(256), 0, stream, partials, out);
}